// Round 3
// baseline (288.816 us; speedup 1.0000x reference)
//
#include <hip/hip_runtime.h>

typedef float v4f __attribute__((ext_vector_type(4)));
typedef short v8s __attribute__((ext_vector_type(8)));

#define BM 64

__device__ __forceinline__ unsigned short f2bf(float f) {
    union { float f; unsigned u; } v; v.f = f;
    unsigned u = v.u;
    u += 0x7FFFu + ((u >> 16) & 1u);   // round-to-nearest-even
    return (unsigned short)(u >> 16);
}

// pack two f32 -> two bf16 (RNE) in one instruction
__device__ __forceinline__ unsigned cvt_pk_bf16(float lo, float hi) {
    unsigned r;
    asm("v_cvt_pk_bf16_f32 %0, %1, %2" : "=v"(r) : "v"(lo), "v"(hi));
    return r;
}

__device__ __forceinline__ float fast_exp2(float x) {
#if __has_builtin(__builtin_amdgcn_exp2f)
    return __builtin_amdgcn_exp2f(x);
#else
    return exp2f(x);
#endif
}
__device__ __forceinline__ float fast_rcp(float x) {
#if __has_builtin(__builtin_amdgcn_rcpf)
    return __builtin_amdgcn_rcpf(x);
#else
    return 1.0f / x;
#endif
}
__device__ __forceinline__ float fast_tanh(float y) {
    float t = fast_exp2(y * 2.885390081777927f);
    return (t - 1.0f) * fast_rcp(t + 1.0f);
}
__device__ __forceinline__ float fast_sigmoid(float z) {
    float t = fast_exp2(-1.4426950408889634f * z);
    return fast_rcp(1.0f + t);
}

// ---------------------------------------------------------------------------
// Pack 5 weight matrices (fp32 row-major [N][K]) into bf16 MFMA-B-fragment
// order (canonical 16x32 tile: lane = ((k>>3)&3)*16 + (n&15), j = k&7).
// ws layout: Wb(98304) | W1(65536) | W2 | Wa | Wt   (bf16 elems)
// ---------------------------------------------------------------------------
__global__ void prep_pack(const float* __restrict__ Wb, const float* __restrict__ W1,
                          const float* __restrict__ W2, const float* __restrict__ Wa,
                          const float* __restrict__ Wt, unsigned short* __restrict__ ws)
{
    int e = blockIdx.x * 256 + threadIdx.x;
    if (e >= 360448) return;
    const float* src; int K; int base;
    if (e < 98304)       { src = Wb; K = 384; base = 0; }
    else if (e < 163840) { src = W1; K = 256; base = 98304; }
    else if (e < 229376) { src = W2; K = 256; base = 163840; }
    else if (e < 294912) { src = Wa; K = 256; base = 229376; }
    else                 { src = Wt; K = 256; base = 294912; }
    int le   = e - base;
    int j    = le & 7;
    int lane = (le >> 3) & 63;
    int tile = le >> 9;
    int kt   = K >> 5;
    int ks   = tile % kt;
    int nt   = tile / kt;
    int n = nt * 16 + (lane & 15);
    int k = ks * 32 + (lane >> 4) * 8 + j;
    ws[e] = f2bf(src[n * K + k]);
}

// ---------------------------------------------------------------------------
// Fused CfC cell, BM=64 rows/block, 4 waves each owning 64 output cols.
// LDS 32KB -> 4 blocks/CU (grid = 1024 = exactly 4/CU).
// phase 1: X = lecun_tanh([in|hx] @ Wb^T + bb)   (K=384), double-buffered
//          staging (T14 issue-early/write-late), buffers at lds[0]/lds[8192].
// phase 2: 4 simultaneous GEMMs over X (K=256) + fused epilogue, ks fully
//          unrolled so B loads pipeline against MFMAs.
// ---------------------------------------------------------------------------
__global__ __launch_bounds__(256, 4) void cfc_fused(
    const float* __restrict__ xin, const float* __restrict__ hx,
    const float* __restrict__ ts,
    const float* __restrict__ bb, const float* __restrict__ b1,
    const float* __restrict__ b2, const float* __restrict__ ba,
    const float* __restrict__ bt,
    const unsigned short* __restrict__ wpk,
    float* __restrict__ out)
{
    __shared__ unsigned short lds[16384];   // 32 KB total (2x16KB staging, then X)
    const int tid  = threadIdx.x;
    const int lane = tid & 63;
    const int w    = tid >> 6;        // wave id = output-col group (64 cols)
    const int row0 = blockIdx.x * BM;

    // ---------------- phase 1: backbone GEMM, acc[nt][mt] -------------------
    v4f acc[4][4];
    #pragma unroll
    for (int nt = 0; nt < 4; ++nt) {
        float bv = bb[w * 64 + nt * 16 + (lane & 15)];
        v4f bvv = {bv, bv, bv, bv};
        #pragma unroll
        for (int mt = 0; mt < 4; ++mt) acc[nt][mt] = bvv;
    }

    v4f stg[8];
    auto ISSUE = [&](int c) {
        const float* src = (c == 0) ? (xin + (size_t)row0 * 128)
                                    : (hx + (size_t)row0 * 256 + (c == 2 ? 128 : 0));
        const int srcld = (c == 0) ? 128 : 256;
        #pragma unroll
        for (int it = 0; it < 8; ++it) {
            int i  = tid + it * 256;
            int r  = i >> 5;
            int c4 = i & 31;
            stg[it] = __builtin_nontemporal_load(
                reinterpret_cast<const v4f*>(src + (size_t)r * srcld) + c4);
        }
    };
    auto WRITE = [&](int boff) {
        #pragma unroll
        for (int it = 0; it < 8; ++it) {
            int i  = tid + it * 256;
            int r  = i >> 5;
            int c4 = i & 31;
            uint2 pk;
            pk.x = cvt_pk_bf16(stg[it][0], stg[it][1]);
            pk.y = cvt_pk_bf16(stg[it][2], stg[it][3]);
            int idx = (((r >> 4) * 4 + (c4 >> 3)) * 64 + ((c4 >> 1) & 3) * 16 + (r & 15)) * 8
                      + (c4 & 1) * 4;
            *reinterpret_cast<uint2*>(&lds[boff + idx]) = pk;
        }
    };
    auto COMPUTE = [&](int c, int boff) {
        #pragma unroll
        for (int ksl = 0; ksl < 4; ++ksl) {
            v8s a[4];
            #pragma unroll
            for (int mt = 0; mt < 4; ++mt)
                a[mt] = *reinterpret_cast<const v8s*>(&lds[boff + ((mt*4 + ksl)*64 + lane)*8]);
            const int gks = c * 4 + ksl;
            #pragma unroll
            for (int nt = 0; nt < 4; ++nt) {
                v8s b = *reinterpret_cast<const v8s*>(
                            wpk + ((size_t)((w*4 + nt)*12 + gks)*64 + lane)*8);
                #pragma unroll
                for (int mt = 0; mt < 4; ++mt)
                    acc[nt][mt] = __builtin_amdgcn_mfma_f32_16x16x32_bf16(a[mt], b, acc[nt][mt], 0, 0, 0);
            }
        }
    };

    ISSUE(0); WRITE(0);
    __syncthreads();
    ISSUE(1); COMPUTE(0, 0);     WRITE(8192);
    __syncthreads();
    ISSUE(2); COMPUTE(1, 8192);  WRITE(0);
    __syncthreads();
    COMPUTE(2, 0);

    // hoisted phase-2 bias loads (latency hides under activation + barrier)
    float hb0[4], hb1[4], hb2[4], hb3[4];
    #pragma unroll
    for (int g = 0; g < 4; ++g) {
        int n = w * 64 + g * 16 + (lane & 15);
        hb0[g] = b1[n]; hb1[g] = b2[n]; hb2[g] = ba[n]; hb3[g] = bt[n];
    }

    __syncthreads();

    // ------------- activation + write X to LDS in packed A-frag layout ------
    // D elem: row = mt*16+(lane>>4)*4+r, k2 = w*64+nt*16+(lane&15)
    #pragma unroll
    for (int nt = 0; nt < 4; ++nt)
        #pragma unroll
        for (int mt = 0; mt < 4; ++mt)
            #pragma unroll
            for (int r = 0; r < 4; ++r) {
                float xv = 1.7159f * fast_tanh(0.666f * acc[nt][mt][r]);
                int idx = ((mt*8 + w*2 + (nt >> 1)) * 64
                           + ((nt & 1)*2 + ((lane >> 3) & 1)) * 16 + (lane >> 4)*4 + r) * 8
                          + (lane & 7);
                lds[idx] = f2bf(xv);
            }
    __syncthreads();

    // ---------------- phase 2: 4 GEMMs over X + fused epilogue --------------
    const unsigned short* wmp = wpk + 98304;   // W1,W2,Wa,Wt each 65536 elems
    #pragma unroll 1
    for (int g = 0; g < 4; ++g) {              // n-tiles (16 cols each)
        const int n = w * 64 + g * 16 + (lane & 15);
        v4f a2[4][4];                          // [mat][mt]
        {
            v4f q1 = {hb0[g],hb0[g],hb0[g],hb0[g]};
            v4f q2 = {hb1[g],hb1[g],hb1[g],hb1[g]};
            v4f qa = {hb2[g],hb2[g],hb2[g],hb2[g]};
            v4f qt = {hb3[g],hb3[g],hb3[g],hb3[g]};
            #pragma unroll
            for (int mt = 0; mt < 4; ++mt) {
                a2[0][mt] = q1; a2[1][mt] = q2; a2[2][mt] = qa; a2[3][mt] = qt;
            }
        }
        #pragma unroll
        for (int ks = 0; ks < 8; ++ks) {
            v8s a[4];
            #pragma unroll
            for (int mt = 0; mt < 4; ++mt)
                a[mt] = *reinterpret_cast<const v8s*>(&lds[((mt*8 + ks)*64 + lane)*8]);
            const int tile = ((w*4 + g)*8 + ks)*64;
            #pragma unroll
            for (int mat = 0; mat < 4; ++mat) {
                v8s b = *reinterpret_cast<const v8s*>(wmp + (size_t)mat*65536 + ((size_t)tile + lane)*8);
                #pragma unroll
                for (int mt = 0; mt < 4; ++mt)
                    a2[mat][mt] = __builtin_amdgcn_mfma_f32_16x16x32_bf16(a[mt], b, a2[mat][mt], 0, 0, 0);
            }
        }
        // fused epilogue: ff1, ff2, t_interp, blend, store
        #pragma unroll
        for (int mt = 0; mt < 4; ++mt) {
            int rowb = row0 + mt*16 + ((lane >> 4) << 2);
            #pragma unroll
            for (int r = 0; r < 4; ++r) {
                float tsv = ts[rowb + r];
                float ff1 = fast_tanh(a2[0][mt][r]);
                float ff2 = fast_tanh(a2[1][mt][r]);
                float ti  = fast_sigmoid(a2[2][mt][r] * tsv + a2[3][mt][r]);
                __builtin_nontemporal_store(ff1 + ti * (ff2 - ff1),
                                            &out[(size_t)(rowb + r) * 256 + n]);
            }
        }
    }
}

extern "C" void kernel_launch(void* const* d_in, const int* in_sizes, int n_in,
                              void* d_out, int out_size, void* d_ws, size_t ws_size,
                              hipStream_t stream)
{
    const float* xin = (const float*)d_in[0];
    const float* hx  = (const float*)d_in[1];
    const float* ts  = (const float*)d_in[2];
    const float* Wb  = (const float*)d_in[3];
    const float* bb  = (const float*)d_in[4];
    const float* W1  = (const float*)d_in[5];
    const float* b1  = (const float*)d_in[6];
    const float* W2  = (const float*)d_in[7];
    const float* b2  = (const float*)d_in[8];
    const float* Wa  = (const float*)d_in[9];
    const float* ba  = (const float*)d_in[10];
    const float* Wt  = (const float*)d_in[11];
    const float* bt  = (const float*)d_in[12];

    if (ws_size < 360448 * sizeof(unsigned short)) return;
    unsigned short* wpk = (unsigned short*)d_ws;

    prep_pack<<<1408, 256, 0, stream>>>(Wb, W1, W2, Wa, Wt, wpk);
    cfc_fused<<<1024, 256, 0, stream>>>(xin, hx, ts, bb, b1, b2, ba, bt, wpk,
                                        (float*)d_out);
}

// Round 4
// 166.130 us; speedup vs baseline: 1.7385x; 1.7385x over previous
//
#include <hip/hip_runtime.h>

typedef float v4f __attribute__((ext_vector_type(4)));
typedef short v8s __attribute__((ext_vector_type(8)));

#define BM 64

__device__ __forceinline__ unsigned short f2bf(float f) {
    union { float f; unsigned u; } v; v.f = f;
    unsigned u = v.u;
    u += 0x7FFFu + ((u >> 16) & 1u);   // round-to-nearest-even
    return (unsigned short)(u >> 16);
}

// pack two f32 -> two bf16 (RNE) in one instruction
__device__ __forceinline__ unsigned cvt_pk_bf16(float lo, float hi) {
    unsigned r;
    asm("v_cvt_pk_bf16_f32 %0, %1, %2" : "=v"(r) : "v"(lo), "v"(hi));
    return r;
}

__device__ __forceinline__ float fast_exp2(float x) {
#if __has_builtin(__builtin_amdgcn_exp2f)
    return __builtin_amdgcn_exp2f(x);
#else
    return exp2f(x);
#endif
}
__device__ __forceinline__ float fast_rcp(float x) {
#if __has_builtin(__builtin_amdgcn_rcpf)
    return __builtin_amdgcn_rcpf(x);
#else
    return 1.0f / x;
#endif
}
__device__ __forceinline__ float fast_tanh(float y) {
    float t = fast_exp2(y * 2.885390081777927f);
    return (t - 1.0f) * fast_rcp(t + 1.0f);
}
__device__ __forceinline__ float fast_sigmoid(float z) {
    float t = fast_exp2(-1.4426950408889634f * z);
    return fast_rcp(1.0f + t);
}

// ---------------------------------------------------------------------------
// Pack 5 weight matrices (fp32 row-major [N][K]) into bf16 MFMA-B-fragment
// order (canonical 16x32 tile: lane = ((k>>3)&3)*16 + (n&15), j = k&7).
// ws layout: Wb(98304) | W1(65536) | W2 | Wa | Wt   (bf16 elems)
// ---------------------------------------------------------------------------
__global__ void prep_pack(const float* __restrict__ Wb, const float* __restrict__ W1,
                          const float* __restrict__ W2, const float* __restrict__ Wa,
                          const float* __restrict__ Wt, unsigned short* __restrict__ ws)
{
    int e = blockIdx.x * 256 + threadIdx.x;
    if (e >= 360448) return;
    const float* src; int K; int base;
    if (e < 98304)       { src = Wb; K = 384; base = 0; }
    else if (e < 163840) { src = W1; K = 256; base = 98304; }
    else if (e < 229376) { src = W2; K = 256; base = 163840; }
    else if (e < 294912) { src = Wa; K = 256; base = 229376; }
    else                 { src = Wt; K = 256; base = 294912; }
    int le   = e - base;
    int j    = le & 7;
    int lane = (le >> 3) & 63;
    int tile = le >> 9;
    int kt   = K >> 5;
    int ks   = tile % kt;
    int nt   = tile / kt;
    int n = nt * 16 + (lane & 15);
    int k = ks * 32 + (lane >> 4) * 8 + j;
    ws[e] = f2bf(src[n * K + k]);
}

// ---------------------------------------------------------------------------
// Fused CfC cell, BM=64 rows/block, 4 waves each owning 64 output cols.
// LDS 32KB; __launch_bounds__(256,3): ~170 reg/wave total budget so the
// 64-AGPR accumulator + ~100 VGPR pipeline state fit WITHOUT scratch spills.
// phase 1: X = lecun_tanh([in|hx] @ Wb^T + bb)   (K=384)
// phase 2: 4 simultaneous GEMMs over X (K=256) + fused epilogue
// B-weights double-buffered in registers across barrier-free unrolled k-steps.
// ---------------------------------------------------------------------------
__global__ __launch_bounds__(256, 3) void cfc_fused(
    const float* __restrict__ xin, const float* __restrict__ hx,
    const float* __restrict__ ts,
    const float* __restrict__ bb, const float* __restrict__ b1,
    const float* __restrict__ b2, const float* __restrict__ ba,
    const float* __restrict__ bt,
    const unsigned short* __restrict__ wpk,
    float* __restrict__ out)
{
    __shared__ unsigned short lds[16384];   // 32 KB
    const int tid  = threadIdx.x;
    const int lane = tid & 63;
    const int w    = tid >> 6;        // wave id = output-col group (64 cols)
    const int row0 = blockIdx.x * BM;

    // ---------------- phase 1: backbone GEMM, acc[nt][mt] -------------------
    v4f acc[4][4];
    #pragma unroll
    for (int nt = 0; nt < 4; ++nt) {
        float bv = bb[w * 64 + nt * 16 + (lane & 15)];
        v4f bvv = {bv, bv, bv, bv};
        #pragma unroll
        for (int mt = 0; mt < 4; ++mt) acc[nt][mt] = bvv;
    }

    v8s bcur[4], bnxt[4];

    #pragma unroll 1
    for (int c = 0; c < 3; ++c) {   // K chunks: in[0:128], hx[0:128], hx[128:256]
        const float* src = (c == 0) ? (xin + (size_t)row0 * 128)
                                    : (hx + (size_t)row0 * 256 + (c == 2 ? 128 : 0));
        const int srcld = (c == 0) ? 128 : 256;

        // issue B loads for (c, ksl=0) — land during staging
        #pragma unroll
        for (int nt = 0; nt < 4; ++nt)
            bcur[nt] = *reinterpret_cast<const v8s*>(
                           wpk + ((size_t)((w*4 + nt)*12 + c*4)*64 + lane)*8);

        // issue the 8 staging loads (global; no LDS dep -> before barrier)
        v4f stg[8];
        #pragma unroll
        for (int it = 0; it < 8; ++it) {
            int i  = tid + it * 256;
            int r  = i >> 5;
            int c4 = i & 31;
            stg[it] = *(reinterpret_cast<const v4f*>(src + (size_t)r * srcld) + c4);
        }

        __syncthreads();            // previous chunk fully consumed
        #pragma unroll
        for (int it = 0; it < 8; ++it) {
            int i  = tid + it * 256;
            int r  = i >> 5;
            int c4 = i & 31;
            uint2 pk;
            pk.x = cvt_pk_bf16(stg[it][0], stg[it][1]);
            pk.y = cvt_pk_bf16(stg[it][2], stg[it][3]);
            int idx = (((r >> 4) * 4 + (c4 >> 3)) * 64 + ((c4 >> 1) & 3) * 16 + (r & 15)) * 8
                      + (c4 & 1) * 4;
            *reinterpret_cast<uint2*>(&lds[idx]) = pk;
        }
        __syncthreads();

        #pragma unroll
        for (int ksl = 0; ksl < 4; ++ksl) {
            // prefetch next k-step's B while this step's MFMAs run
            if (ksl < 3) {
                #pragma unroll
                for (int nt = 0; nt < 4; ++nt)
                    bnxt[nt] = *reinterpret_cast<const v8s*>(
                                   wpk + ((size_t)((w*4 + nt)*12 + c*4 + ksl + 1)*64 + lane)*8);
            }
            v8s a[4];
            #pragma unroll
            for (int mt = 0; mt < 4; ++mt)
                a[mt] = *reinterpret_cast<const v8s*>(&lds[((mt*4 + ksl)*64 + lane)*8]);
            #pragma unroll
            for (int nt = 0; nt < 4; ++nt)
                #pragma unroll
                for (int mt = 0; mt < 4; ++mt)
                    acc[nt][mt] = __builtin_amdgcn_mfma_f32_16x16x32_bf16(a[mt], bcur[nt], acc[nt][mt], 0, 0, 0);
            if (ksl < 3) {
                #pragma unroll
                for (int nt = 0; nt < 4; ++nt) bcur[nt] = bnxt[nt];
            }
        }
    }

    // prefetch phase-2 g=0, ks=0 B fragments (land during activation+barrier)
    const unsigned short* wmp = wpk + 98304;   // W1,W2,Wa,Wt each 65536 elems
    #pragma unroll
    for (int mat = 0; mat < 4; ++mat)
        bcur[mat] = *reinterpret_cast<const v8s*>(
                        wmp + (size_t)mat*65536 + ((size_t)(w*4*8)*64 + lane)*8);

    __syncthreads();

    // ------------- activation + write X to LDS in packed A-frag layout ------
    // D elem: row = mt*16+(lane>>4)*4+r, k2 = w*64+nt*16+(lane&15)
    #pragma unroll
    for (int nt = 0; nt < 4; ++nt)
        #pragma unroll
        for (int mt = 0; mt < 4; ++mt)
            #pragma unroll
            for (int r = 0; r < 4; ++r) {
                float xv = 1.7159f * fast_tanh(0.666f * acc[nt][mt][r]);
                int idx = ((mt*8 + w*2 + (nt >> 1)) * 64
                           + ((nt & 1)*2 + ((lane >> 3) & 1)) * 16 + (lane >> 4)*4 + r) * 8
                          + (lane & 7);
                lds[idx] = f2bf(xv);
            }
    __syncthreads();

    // ---------------- phase 2: 4 GEMMs over X + fused epilogue --------------
    #pragma unroll 1
    for (int g = 0; g < 4; ++g) {              // n-tiles (16 cols each)
        const int n = w * 64 + g * 16 + (lane & 15);
        v4f a2[4][4];                          // [mat][mt]
        {
            float v1 = b1[n], v2 = b2[n], va = ba[n], vt = bt[n];
            v4f q1 = {v1,v1,v1,v1}, q2 = {v2,v2,v2,v2}, qa = {va,va,va,va}, qt = {vt,vt,vt,vt};
            #pragma unroll
            for (int mt = 0; mt < 4; ++mt) {
                a2[0][mt] = q1; a2[1][mt] = q2; a2[2][mt] = qa; a2[3][mt] = qt;
            }
        }
        #pragma unroll
        for (int ks = 0; ks < 8; ++ks) {
            // prefetch next k-step (wraps into next g's ks=0; g=3 wraps to g=0,
            // a harmless always-valid redundant load)
            {
                const int nks = (ks + 1) & 7;
                const int ng  = (ks == 7) ? ((g + 1) & 3) : g;
                const int tile = ((w*4 + ng)*8 + nks)*64;
                #pragma unroll
                for (int mat = 0; mat < 4; ++mat)
                    bnxt[mat] = *reinterpret_cast<const v8s*>(
                                    wmp + (size_t)mat*65536 + ((size_t)tile + lane)*8);
            }
            v8s a[4];
            #pragma unroll
            for (int mt = 0; mt < 4; ++mt)
                a[mt] = *reinterpret_cast<const v8s*>(&lds[((mt*8 + ks)*64 + lane)*8]);
            #pragma unroll
            for (int mat = 0; mat < 4; ++mat)
                #pragma unroll
                for (int mt = 0; mt < 4; ++mt)
                    a2[mat][mt] = __builtin_amdgcn_mfma_f32_16x16x32_bf16(a[mt], bcur[mat], a2[mat][mt], 0, 0, 0);
            #pragma unroll
            for (int mat = 0; mat < 4; ++mat) bcur[mat] = bnxt[mat];
        }
        // fused epilogue: ff1, ff2, t_interp, blend, store
        #pragma unroll
        for (int mt = 0; mt < 4; ++mt) {
            int rowb = row0 + mt*16 + ((lane >> 4) << 2);
            #pragma unroll
            for (int r = 0; r < 4; ++r) {
                float tsv = ts[rowb + r];
                float ff1 = fast_tanh(a2[0][mt][r]);
                float ff2 = fast_tanh(a2[1][mt][r]);
                float ti  = fast_sigmoid(a2[2][mt][r] * tsv + a2[3][mt][r]);
                out[(size_t)(rowb + r) * 256 + n] = ff1 + ti * (ff2 - ff1);
            }
        }
    }
}

extern "C" void kernel_launch(void* const* d_in, const int* in_sizes, int n_in,
                              void* d_out, int out_size, void* d_ws, size_t ws_size,
                              hipStream_t stream)
{
    const float* xin = (const float*)d_in[0];
    const float* hx  = (const float*)d_in[1];
    const float* ts  = (const float*)d_in[2];
    const float* Wb  = (const float*)d_in[3];
    const float* bb  = (const float*)d_in[4];
    const float* W1  = (const float*)d_in[5];
    const float* b1  = (const float*)d_in[6];
    const float* W2  = (const float*)d_in[7];
    const float* b2  = (const float*)d_in[8];
    const float* Wa  = (const float*)d_in[9];
    const float* ba  = (const float*)d_in[10];
    const float* Wt  = (const float*)d_in[11];
    const float* bt  = (const float*)d_in[12];

    if (ws_size < 360448 * sizeof(unsigned short)) return;
    unsigned short* wpk = (unsigned short*)d_ws;

    prep_pack<<<1408, 256, 0, stream>>>(Wb, W1, W2, Wa, Wt, wpk);
    cfc_fused<<<1024, 256, 0, stream>>>(xin, hx, ts, bb, b1, b2, ba, bt, wpk,
                                        (float*)d_out);
}

// Round 5
// 115.770 us; speedup vs baseline: 2.4947x; 1.4350x over previous
//
#include <hip/hip_runtime.h>

typedef float v4f __attribute__((ext_vector_type(4)));
typedef short v8s __attribute__((ext_vector_type(8)));

#define BM 32

__device__ __forceinline__ unsigned short f2bf(float f) {
    union { float f; unsigned u; } v; v.f = f;
    unsigned u = v.u;
    u += 0x7FFFu + ((u >> 16) & 1u);   // round-to-nearest-even
    return (unsigned short)(u >> 16);
}

// pack two f32 -> two bf16 (RNE) in one instruction
__device__ __forceinline__ unsigned cvt_pk_bf16(float lo, float hi) {
    unsigned r;
    asm("v_cvt_pk_bf16_f32 %0, %1, %2" : "=v"(r) : "v"(lo), "v"(hi));
    return r;
}

__device__ __forceinline__ float fast_exp2(float x) {
#if __has_builtin(__builtin_amdgcn_exp2f)
    return __builtin_amdgcn_exp2f(x);
#else
    return exp2f(x);
#endif
}
__device__ __forceinline__ float fast_rcp(float x) {
#if __has_builtin(__builtin_amdgcn_rcpf)
    return __builtin_amdgcn_rcpf(x);
#else
    return 1.0f / x;
#endif
}
__device__ __forceinline__ float fast_tanh(float y) {
    float t = fast_exp2(y * 2.885390081777927f);
    return (t - 1.0f) * fast_rcp(t + 1.0f);
}
__device__ __forceinline__ float fast_sigmoid(float z) {
    float t = fast_exp2(-1.4426950408889634f * z);
    return fast_rcp(1.0f + t);
}

// ---------------------------------------------------------------------------
// Pack 5 weight matrices (fp32 row-major [N][K]) into bf16 MFMA-B-fragment
// order (canonical 16x32 tile: lane = ((k>>3)&3)*16 + (n&15), j = k&7).
// ws layout: Wb(98304) | W1(65536) | W2 | Wa | Wt   (bf16 elems)
// ---------------------------------------------------------------------------
__global__ void prep_pack(const float* __restrict__ Wb, const float* __restrict__ W1,
                          const float* __restrict__ W2, const float* __restrict__ Wa,
                          const float* __restrict__ Wt, unsigned short* __restrict__ ws)
{
    int e = blockIdx.x * 256 + threadIdx.x;
    if (e >= 360448) return;
    const float* src; int K; int base;
    if (e < 98304)       { src = Wb; K = 384; base = 0; }
    else if (e < 163840) { src = W1; K = 256; base = 98304; }
    else if (e < 229376) { src = W2; K = 256; base = 163840; }
    else if (e < 294912) { src = Wa; K = 256; base = 229376; }
    else                 { src = Wt; K = 256; base = 294912; }
    int le   = e - base;
    int j    = le & 7;
    int lane = (le >> 3) & 63;
    int tile = le >> 9;
    int kt   = K >> 5;
    int ks   = tile % kt;
    int nt   = tile / kt;
    int n = nt * 16 + (lane & 15);
    int k = ks * 32 + (lane >> 4) * 8 + j;
    ws[e] = f2bf(src[n * K + k]);
}

// ---------------------------------------------------------------------------
// Fused CfC cell, BM=32 rows/block, 4 waves each owning 64 output cols x 32
// rows. acc = 32 AGPR -> total regs ~82, fits __launch_bounds__(256,6):
// 6 blocks/CU = 24 waves/CU (75% occupancy). LDS 16 KB (staging 8 KB overlay).
// Same fragment layouts / barrier structure as the verified Round-2 kernel.
// phase 1: X = lecun_tanh([in|hx] @ Wb^T + bb)   (K=384)
// phase 2: 4 simultaneous GEMMs over X (K=256) + fused epilogue
// ---------------------------------------------------------------------------
__global__ __launch_bounds__(256, 6) void cfc_fused(
    const float* __restrict__ xin, const float* __restrict__ hx,
    const float* __restrict__ ts,
    const float* __restrict__ bb, const float* __restrict__ b1,
    const float* __restrict__ b2, const float* __restrict__ ba,
    const float* __restrict__ bt,
    const unsigned short* __restrict__ wpk,
    float* __restrict__ out)
{
    __shared__ unsigned short lds[8192];   // 16 KB
    const int tid  = threadIdx.x;
    const int lane = tid & 63;
    const int w    = tid >> 6;        // wave id = output-col group (64 cols)
    const int row0 = blockIdx.x * BM;

    // ---------------- phase 1: backbone GEMM, acc[nt][mt] -------------------
    v4f acc[4][2];
    #pragma unroll
    for (int nt = 0; nt < 4; ++nt) {
        float bv = bb[w * 64 + nt * 16 + (lane & 15)];
        v4f bvv = {bv, bv, bv, bv};
        #pragma unroll
        for (int mt = 0; mt < 2; ++mt) acc[nt][mt] = bvv;
    }

    #pragma unroll 1
    for (int c = 0; c < 3; ++c) {   // K chunks: in[0:128], hx[0:128], hx[128:256]
        const float* src = (c == 0) ? (xin + (size_t)row0 * 128)
                                    : (hx + (size_t)row0 * 256 + (c == 2 ? 128 : 0));
        const int srcld = (c == 0) ? 128 : 256;
        __syncthreads();            // previous chunk fully consumed
        #pragma unroll
        for (int it = 0; it < 4; ++it) {
            int i  = tid + it * 256;        // 0..1023 float4s of a 32x128 tile
            int r  = i >> 5;
            int c4 = i & 31;
            v4f v = *(reinterpret_cast<const v4f*>(src + (size_t)r * srcld) + c4);
            uint2 pk;
            pk.x = cvt_pk_bf16(v[0], v[1]);
            pk.y = cvt_pk_bf16(v[2], v[3]);
            int idx = (((r >> 4) * 4 + (c4 >> 3)) * 64 + ((c4 >> 1) & 3) * 16 + (r & 15)) * 8
                      + (c4 & 1) * 4;
            *reinterpret_cast<uint2*>(&lds[idx]) = pk;
        }
        __syncthreads();
        #pragma unroll 1
        for (int ksl = 0; ksl < 4; ++ksl) {
            v8s a[2];
            #pragma unroll
            for (int mt = 0; mt < 2; ++mt)
                a[mt] = *reinterpret_cast<const v8s*>(&lds[((mt*4 + ksl)*64 + lane)*8]);
            const int gks = c * 4 + ksl;
            #pragma unroll
            for (int nt = 0; nt < 4; ++nt) {
                v8s b = *reinterpret_cast<const v8s*>(
                            wpk + ((size_t)((w*4 + nt)*12 + gks)*64 + lane)*8);
                #pragma unroll
                for (int mt = 0; mt < 2; ++mt)
                    acc[nt][mt] = __builtin_amdgcn_mfma_f32_16x16x32_bf16(a[mt], b, acc[nt][mt], 0, 0, 0);
            }
        }
    }
    __syncthreads();

    // ------------- activation + write X to LDS in packed A-frag layout ------
    // D elem: row = mt*16+(lane>>4)*4+r, k2 = w*64+nt*16+(lane&15)
    #pragma unroll
    for (int nt = 0; nt < 4; ++nt)
        #pragma unroll
        for (int mt = 0; mt < 2; ++mt)
            #pragma unroll
            for (int r = 0; r < 4; ++r) {
                float xv = 1.7159f * fast_tanh(0.666f * acc[nt][mt][r]);
                int idx = ((mt*8 + w*2 + (nt >> 1)) * 64
                           + ((nt & 1)*2 + ((lane >> 3) & 1)) * 16 + (lane >> 4)*4 + r) * 8
                          + (lane & 7);
                lds[idx] = f2bf(xv);
            }
    __syncthreads();

    // ---------------- phase 2: 4 GEMMs over X + fused epilogue --------------
    const unsigned short* wmp = wpk + 98304;   // W1,W2,Wa,Wt each 65536 elems
    #pragma unroll 1
    for (int g = 0; g < 4; ++g) {              // n-tiles (16 cols each)
        const int n = w * 64 + g * 16 + (lane & 15);
        v4f a2[4][2];                          // [mat][mt]
        {
            float v1 = b1[n], v2 = b2[n], va = ba[n], vt = bt[n];
            v4f q1 = {v1,v1,v1,v1}, q2 = {v2,v2,v2,v2}, qa = {va,va,va,va}, qt = {vt,vt,vt,vt};
            #pragma unroll
            for (int mt = 0; mt < 2; ++mt) {
                a2[0][mt] = q1; a2[1][mt] = q2; a2[2][mt] = qa; a2[3][mt] = qt;
            }
        }
        #pragma unroll 1
        for (int ks = 0; ks < 8; ++ks) {
            v8s a[2];
            #pragma unroll
            for (int mt = 0; mt < 2; ++mt)
                a[mt] = *reinterpret_cast<const v8s*>(&lds[((mt*8 + ks)*64 + lane)*8]);
            const int tile = ((w*4 + g)*8 + ks)*64;
            #pragma unroll
            for (int mat = 0; mat < 4; ++mat) {
                v8s b = *reinterpret_cast<const v8s*>(wmp + (size_t)mat*65536 + ((size_t)tile + lane)*8);
                #pragma unroll
                for (int mt = 0; mt < 2; ++mt)
                    a2[mat][mt] = __builtin_amdgcn_mfma_f32_16x16x32_bf16(a[mt], b, a2[mat][mt], 0, 0, 0);
            }
        }
        // fused epilogue: ff1, ff2, t_interp, blend, store
        #pragma unroll
        for (int mt = 0; mt < 2; ++mt) {
            int rowb = row0 + mt*16 + ((lane >> 4) << 2);
            #pragma unroll
            for (int r = 0; r < 4; ++r) {
                float tsv = ts[rowb + r];
                float ff1 = fast_tanh(a2[0][mt][r]);
                float ff2 = fast_tanh(a2[1][mt][r]);
                float ti  = fast_sigmoid(a2[2][mt][r] * tsv + a2[3][mt][r]);
                out[(size_t)(rowb + r) * 256 + n] = ff1 + ti * (ff2 - ff1);
            }
        }
    }
}

extern "C" void kernel_launch(void* const* d_in, const int* in_sizes, int n_in,
                              void* d_out, int out_size, void* d_ws, size_t ws_size,
                              hipStream_t stream)
{
    const float* xin = (const float*)d_in[0];
    const float* hx  = (const float*)d_in[1];
    const float* ts  = (const float*)d_in[2];
    const float* Wb  = (const float*)d_in[3];
    const float* bb  = (const float*)d_in[4];
    const float* W1  = (const float*)d_in[5];
    const float* b1  = (const float*)d_in[6];
    const float* W2  = (const float*)d_in[7];
    const float* b2  = (const float*)d_in[8];
    const float* Wa  = (const float*)d_in[9];
    const float* ba  = (const float*)d_in[10];
    const float* Wt  = (const float*)d_in[11];
    const float* bt  = (const float*)d_in[12];

    if (ws_size < 360448 * sizeof(unsigned short)) return;
    unsigned short* wpk = (unsigned short*)d_ws;

    prep_pack<<<1408, 256, 0, stream>>>(Wb, W1, W2, Wa, Wt, wpk);
    cfc_fused<<<2048, 256, 0, stream>>>(xin, hx, ts, bb, b1, b2, ba, bt, wpk,
                                        (float*)d_out);
}